// Round 5
// baseline (290.164 us; speedup 1.0000x reference)
//
#include <hip/hip_runtime.h>

#define NN   10000
#define EE   160000
#define CINC 32
#define COUTC 32
#define RRR  6
#define MMM  3
#define RM   (RRR*MMM)      // 18
#define KK   (RM*CINC)      // 576
#define NPB  4              // nodes per block in k_conv
#define PART_STRIDE 132     // 4*32 + 4 pad (float2 units) per chunk
#define EPSV 1e-8f

// ---------------- prep: zero counts + phased weights (merged) ----------------

__global__ void k_prep(int* __restrict__ counts,
                       const float* __restrict__ w1, const float* __restrict__ off1,
                       const float* __restrict__ w2, const float* __restrict__ off2,
                       float2* __restrict__ Wc1, float2* __restrict__ Wc2) {
    int i = blockIdx.x*blockDim.x + threadIdx.x;
    if (i < NN+1) counts[i] = 0;
    if (i < KK*COUTC) {
        int d = i % COUTC;
        int c = (i / COUTC) % CINC;
        float o1 = off1[c*COUTC + d];
        float o2 = off2[c*COUTC + d];
        float s1 = sinf(o1), c1 = cosf(o1);
        float s2 = sinf(o2), c2 = cosf(o2);
        Wc1[i] = make_float2(w1[i]*c1, w1[i]*s1);
        Wc2[i] = make_float2(w2[i]*c2, w2[i]*s2);
    }
}

__global__ void k_hist(const int* __restrict__ edges, int* __restrict__ counts) {
    int i = blockIdx.x*blockDim.x + threadIdx.x;
    if (i < EE) atomicAdd(&counts[edges[2*i+1]], 1);
}

__global__ void k_scan(int* __restrict__ counts, int* __restrict__ cursor) {
    __shared__ int sums[1024];
    const int CH = 10;                 // 1024*10 >= 10000
    int t = threadIdx.x;
    int beg = t*CH;
    int end = beg + CH; if (end > NN) end = NN;
    int local[CH];
    int s = 0;
    for (int i = beg; i < end; ++i) { int v = counts[i]; local[i-beg] = v; s += v; }
    sums[t] = s;
    __syncthreads();
    for (int off = 1; off < 1024; off <<= 1) {
        int v = 0;
        if (t >= off) v = sums[t-off];
        __syncthreads();
        if (t >= off) sums[t] += v;
        __syncthreads();
    }
    int run = sums[t] - s;             // exclusive prefix
    for (int i = beg; i < end; ++i) { counts[i] = run; cursor[i] = run; run += local[i-beg]; }
    if (t == 1023) counts[NN] = run;   // == EE
}

// scatter src index AND the 144B stencil row into target-sorted order
// (fuses the old k_scatter + k_reorder: reads stenc sequentially, writes
// scattered 144B segments; no eids array, one less pass).
__global__ void k_scatter(const int* __restrict__ edges, int* __restrict__ cursor,
                          const float4* __restrict__ stenc4,
                          int* __restrict__ srcs, float4* __restrict__ stens4) {
    int i = blockIdx.x*blockDim.x + threadIdx.x;
    if (i < EE) {
        int src = edges[2*i];
        int tgt = edges[2*i+1];
        int pos = atomicAdd(&cursor[tgt], 1);
        srcs[pos] = src;
        const float4* s = stenc4 + (size_t)i * 9;
        float4* d = stens4 + (size_t)pos * 9;
        #pragma unroll
        for (int j = 0; j < 9; ++j) d[j] = s[j];
    }
}

// ---------------- fused conv (+optional residual) + tangent nonlin ----------------
// 4 nodes/block, 1 wave per node. Lane owns c=l&31 and ALL 18 rm; the two
// 32-lane halves process alternate edges. Edge loop is depth-1 software
// pipelined: while edge e's 72 FMAs execute, edge e+2's stencil row (9xfloat4,
// induction-addressed) and x row (src prefetched 2 edges ahead) are in flight.
// Einsum: lane owns a d-pair (float4 Wc loads), 16 chunks x 36 k.

template<bool FINAL>
__global__ void __launch_bounds__(256)
k_conv(const float2* __restrict__ xin,      // (NN,32) complex input
       const int*  __restrict__ offsets,    // (NN+1)
       const int*  __restrict__ srcs,       // (EE) src node, target-sorted
       const float2* __restrict__ stens,    // (EE,18) complex, target-sorted
       const float2* __restrict__ Wc,       // (KK,32) complex
       const float* __restrict__ bias,      // (32)
       const float2* __restrict__ xres,     // (NN,32) original xc (FINAL)
       const float2* __restrict__ resw,     // (32,32) complex (FINAL)
       float2* __restrict__ out)            // (NN,32) complex
{
    __shared__ float2 smem[NPB*KK];         // 18432 B; agg then reused as part
    float2* agg = smem;
    int t = threadIdx.x;

    // ---- edge aggregation ----
    {
        int g = t >> 6;                     // node slot 0..3 (one wave each)
        int l = t & 63;
        int n = blockIdx.x*NPB + g;
        int c = l & 31;
        int h = l >> 5;                     // half: alternate edges
        float2 acc[RM];
        #pragma unroll
        for (int k = 0; k < RM; ++k) acc[k] = make_float2(0.f, 0.f);

        auto cmac9 = [&](const float4* S, float2 X) {
            #pragma unroll
            for (int j = 0; j < 9; ++j) {
                float4 s = S[j];
                acc[2*j].x   = fmaf(s.x, X.x, fmaf(-s.y, X.y, acc[2*j].x));
                acc[2*j].y   = fmaf(s.x, X.y, fmaf( s.y, X.x, acc[2*j].y));
                acc[2*j+1].x = fmaf(s.z, X.x, fmaf(-s.w, X.y, acc[2*j+1].x));
                acc[2*j+1].y = fmaf(s.z, X.y, fmaf( s.w, X.x, acc[2*j+1].y));
            }
        };

        int beg = offsets[n], end = offsets[n+1];
        int e = beg + h;                    // this half's edges: e, e+2, e+4, ...
        const float4* sp = (const float4*)(stens + (size_t)e * RM);
        float4 sA[9], sB[9];
        float2 xA = make_float2(0.f, 0.f), xB;
        int srcN = 0;                       // src for edge e+2
        bool vA = (e < end);
        if (vA) {
            int s0 = srcs[e];
            if (e + 2 < end) srcN = srcs[e + 2];
            #pragma unroll
            for (int j = 0; j < 9; ++j) sA[j] = sp[j];
            xA = xin[(size_t)s0 * CINC + c];
        }
        while (vA) {
            // stage B (edge e+2) while computing A (edge e)
            bool vB = (e + 2 < end);
            int srcNN = 0;
            if (vB) {
                if (e + 4 < end) srcNN = srcs[e + 4];
                const float4* spB = sp + 18;
                #pragma unroll
                for (int j = 0; j < 9; ++j) sB[j] = spB[j];
                xB = xin[(size_t)srcN * CINC + c];
            }
            cmac9(sA, xA);
            if (!vB) break;
            // stage A (edge e+4) while computing B (edge e+2)
            bool vA2 = (e + 4 < end);
            int srcNN2 = 0;
            if (vA2) {
                if (e + 6 < end) srcNN2 = srcs[e + 6];
                const float4* spA = sp + 36;
                #pragma unroll
                for (int j = 0; j < 9; ++j) sA[j] = spA[j];
                xA = xin[(size_t)srcNN * CINC + c];
            }
            cmac9(sB, xB);
            srcN = srcNN2;
            sp += 36; e += 4;
            vA = vA2;
        }
        // merge the two halves (half1 -> half0)
        #pragma unroll
        for (int k = 0; k < RM; ++k) {
            acc[k].x += __shfl_down(acc[k].x, 32, 64);
            acc[k].y += __shfl_down(acc[k].y, 32, 64);
        }
        if (h == 0) {
            #pragma unroll
            for (int k = 0; k < RM; ++k)
                agg[g*KK + k*32 + c] = acc[k];
        }
    }
    __syncthreads();

    // ---- einsum: out[n,d] = sum_k agg[n,k] * Wc[k,d] ----
    int ch = t >> 4;                        // 16 chunks of 36 k's
    int dp = (t & 15) * 2;                  // d-pair base
    int kb = ch * 36;
    float2 p0[NPB], p1[NPB];
    #pragma unroll
    for (int j = 0; j < NPB; ++j) { p0[j] = make_float2(0.f,0.f); p1[j] = make_float2(0.f,0.f); }
    #pragma unroll 6
    for (int q = 0; q < 36; ++q) {
        float4 w = *(const float4*)(Wc + (size_t)(kb + q) * COUTC + dp);
        #pragma unroll
        for (int j = 0; j < NPB; ++j) {
            float2 a = agg[j*KK + kb + q];
            p0[j].x += a.x*w.x - a.y*w.y;
            p0[j].y += a.x*w.y + a.y*w.x;
            p1[j].x += a.x*w.z - a.y*w.w;
            p1[j].y += a.x*w.w + a.y*w.z;
        }
    }
    __syncthreads();                        // all agg reads done; reuse as part
    float2* part = smem;                    // [16][PART_STRIDE] : [ch][j*32+d]
    #pragma unroll
    for (int j = 0; j < NPB; ++j)
        *(float4*)&part[(size_t)ch*PART_STRIDE + j*32 + dp] =
            make_float4(p0[j].x, p0[j].y, p1[j].x, p1[j].y);
    __syncthreads();

    // ---- reduce chunks, residual, nonlinearity ----
    if (t < NPB*32) {
        int j = t >> 5, d = t & 31;
        int n = blockIdx.x*NPB + j;
        float2 hv = make_float2(0.f, 0.f);
        #pragma unroll
        for (int c2 = 0; c2 < 16; ++c2) {
            float2 vv = part[(size_t)c2*PART_STRIDE + j*32 + d];
            hv.x += vv.x; hv.y += vv.y;
        }
        if (FINAL) {
            const float2* xr = xres + (size_t)n * CINC;
            #pragma unroll
            for (int c = 0; c < CINC; ++c) {
                float2 xv = xr[c];
                float2 w = resw[c*COUTC + d];
                hv.x += xv.x*w.x - xv.y*w.y;
                hv.y += xv.x*w.y + xv.y*w.x;
            }
        }
        float mag = sqrtf(hv.x*hv.x + hv.y*hv.y);
        float num = mag + bias[d]; if (num < 0.f) num = 0.f;
        float den = (mag > EPSV) ? mag : EPSV;
        float f = num / den;
        out[(size_t)n*COUTC + d] = make_float2(f*hv.x, f*hv.y);
    }
}

// ---------------- launch ----------------

extern "C" void kernel_launch(void* const* d_in, const int* in_sizes, int n_in,
                              void* d_out, int out_size, void* d_ws, size_t ws_size,
                              hipStream_t stream) {
    const float2* xc   = (const float2*)d_in[0];   // (N,32,2) -> complex
    const int*   edges = (const int*)  d_in[1];    // (E,2)
    const float2* stenc= (const float2*)d_in[2];   // (E,6,3,2) -> (E,18) complex
    const float* w1    = (const float*)d_in[3];
    const float* off1  = (const float*)d_in[4];
    const float* b1    = (const float*)d_in[5];
    const float* w2    = (const float*)d_in[6];
    const float* off2  = (const float*)d_in[7];
    const float* b2    = (const float*)d_in[8];
    const float2* resw = (const float2*)d_in[9];   // (32,32) complex
    float2* out = (float2*)d_out;

    char* ws = (char*)d_ws;
    size_t o = 0;
    auto alloc = [&](size_t bytes) {
        o = (o + 255) & ~(size_t)255;
        size_t r = o; o += bytes; return r;
    };
    int*    counts = (int*)   (ws + alloc((NN+1)*sizeof(int)));
    int*    cursor = (int*)   (ws + alloc(NN*sizeof(int)));
    int*    srcs   = (int*)   (ws + alloc(EE*sizeof(int)));
    float2* stens  = (float2*)(ws + alloc((size_t)EE*RM*sizeof(float2)));
    float2* Wc1    = (float2*)(ws + alloc((size_t)KK*COUTC*sizeof(float2)));
    float2* Wc2    = (float2*)(ws + alloc((size_t)KK*COUTC*sizeof(float2)));
    float2* h      = (float2*)(ws + alloc((size_t)NN*COUTC*sizeof(float2)));
    (void)ws_size; (void)in_sizes; (void)n_in; (void)out_size;

    int prep_n = (KK*COUTC > NN+1) ? KK*COUTC : NN+1;
    k_prep   <<<(prep_n+255)/256, 256, 0, stream>>>(counts, w1, off1, w2, off2, Wc1, Wc2);
    k_hist   <<<(EE+255)/256,   256, 0, stream>>>(edges, counts);
    k_scan   <<<1, 1024, 0, stream>>>(counts, cursor);
    k_scatter<<<(EE+255)/256,   256, 0, stream>>>(edges, cursor, (const float4*)stenc,
                                                  srcs, (float4*)stens);

    k_conv<false><<<NN/NPB, 256, 0, stream>>>(xc, counts, srcs, stens, Wc1, b1,
                                              nullptr, nullptr, h);
    k_conv<true> <<<NN/NPB, 256, 0, stream>>>(h, counts, srcs, stens, Wc2, b2,
                                              xc, resw, out);
}

// Round 6
// 250.178 us; speedup vs baseline: 1.1598x; 1.1598x over previous
//
#include <hip/hip_runtime.h>

#define NN   10000
#define EE   160000
#define CINC 32
#define COUTC 32
#define RRR  6
#define MMM  3
#define RM   (RRR*MMM)      // 18
#define KK   (RM*CINC)      // 576
#define NPB  4              // nodes per block in k_conv
#define CE   16             // edges staged per node per chunk
#define PART_STRIDE 132     // 4*32 + 4 pad (float2 units) per chunk
#define EPSV 1e-8f

// ---------------- prep: phased weights + degree histogram (counts pre-zeroed
// by hipMemsetAsync) ----------------

__global__ void k_prep(const int* __restrict__ edges, int* __restrict__ counts,
                       const float* __restrict__ w1, const float* __restrict__ off1,
                       const float* __restrict__ w2, const float* __restrict__ off2,
                       float2* __restrict__ Wc1, float2* __restrict__ Wc2) {
    int i = blockIdx.x*blockDim.x + threadIdx.x;
    if (i < KK*COUTC) {
        int d = i % COUTC;
        int c = (i / COUTC) % CINC;
        float o1 = off1[c*COUTC + d];
        float o2 = off2[c*COUTC + d];
        float s1 = sinf(o1), c1 = cosf(o1);
        float s2 = sinf(o2), c2 = cosf(o2);
        Wc1[i] = make_float2(w1[i]*c1, w1[i]*s1);
        Wc2[i] = make_float2(w2[i]*c2, w2[i]*s2);
    }
    if (i < EE) atomicAdd(&counts[edges[2*i+1]], 1);
}

__global__ void k_scan(int* __restrict__ counts, int* __restrict__ cursor) {
    __shared__ int sums[1024];
    const int CH = 10;                 // 1024*10 >= 10000
    int t = threadIdx.x;
    int beg = t*CH;
    int end = beg + CH; if (end > NN) end = NN;
    int local[CH];
    int s = 0;
    for (int i = beg; i < end; ++i) { int v = counts[i]; local[i-beg] = v; s += v; }
    sums[t] = s;
    __syncthreads();
    for (int off = 1; off < 1024; off <<= 1) {
        int v = 0;
        if (t >= off) v = sums[t-off];
        __syncthreads();
        if (t >= off) sums[t] += v;
        __syncthreads();
    }
    int run = sums[t] - s;             // exclusive prefix
    for (int i = beg; i < end; ++i) { counts[i] = run; cursor[i] = run; run += local[i-beg]; }
    if (t == 1023) counts[NN] = run;   // == EE
}

// target-sorted (src, eid) — int writes only, no stencil copy
__global__ void k_scatter(const int* __restrict__ edges, int* __restrict__ cursor,
                          int* __restrict__ srcs, int* __restrict__ eids) {
    int i = blockIdx.x*blockDim.x + threadIdx.x;
    if (i < EE) {
        int src = edges[2*i];
        int tgt = edges[2*i+1];
        int pos = atomicAdd(&cursor[tgt], 1);
        srcs[pos] = src;
        eids[pos] = i;
    }
}

// ---------------- fused conv (+optional residual) + tangent nonlin ----------------
// 4 nodes/block, 1 wave per node. Edge phase is chunked (CE=16 edges): the
// wave cooperatively stages the chunk's stencil rows into LDS (eid-indirect,
// up to 144 float4 loads in flight, zero VGPR buffering), then computes from
// LDS via broadcast ds_read_b128. x rows loaded direct (src broadcast via
// shfl, prefetched one edge-pair ahead). No __syncthreads in the edge phase
// (per-wave LDS regions). Einsum: lane owns a d-pair, 16 chunks x 36 k.

template<bool FINAL>
__global__ void __launch_bounds__(256)
k_conv(const float2* __restrict__ xin,      // (NN,32) complex input
       const int*  __restrict__ offsets,    // (NN+1)
       const int*  __restrict__ srcs,       // (EE) src node, target-sorted
       const int*  __restrict__ eids,       // (EE) edge id, target-sorted
       const float4* __restrict__ stenc4,   // (EE,9) float4 = (EE,18) complex
       const float2* __restrict__ Wc,       // (KK,32) complex
       const float* __restrict__ bias,      // (32)
       const float2* __restrict__ xres,     // (NN,32) original xc (FINAL)
       const float2* __restrict__ resw,     // (32,32) complex (FINAL)
       float2* __restrict__ out)            // (NN,32) complex
{
    __shared__ float2 smem[NPB*KK];         // 18432 B; agg then reused as part
    __shared__ float4 sten[NPB*CE*9];       // 9216 B stencil stage
    float2* agg = smem;
    int t = threadIdx.x;

    // ---- edge aggregation ----
    {
        int g = t >> 6;                     // node slot 0..3 (one wave each)
        int l = t & 63;
        int n = blockIdx.x*NPB + g;
        int c = l & 31;
        int h = l >> 5;                     // half: alternate edges
        float4* myst = sten + g*(CE*9);
        float2 acc[RM];
        #pragma unroll
        for (int k = 0; k < RM; ++k) acc[k] = make_float2(0.f, 0.f);

        int beg = offsets[n], end = offsets[n+1];
        for (int eb = beg; eb < end; eb += CE) {
            int ne = end - eb; if (ne > CE) ne = CE;
            int nf4 = ne * 9;
            // stage stencil rows for this chunk (cooperative across the wave)
            for (int idx = l; idx < nf4; idx += 64) {
                int e = idx / 9;
                int comp = idx - e*9;
                int eid = eids[eb + e];
                myst[idx] = stenc4[(size_t)eid*9 + comp];
            }
            int srcv = 0;
            if (l < ne) srcv = srcs[eb + l];

            int le = h;
            float2 xA = make_float2(0.f, 0.f);
            if (le < ne) {
                int s0 = __shfl(srcv, le, 64);
                xA = xin[(size_t)s0 * CINC + c];
            }
            int iters = (ne + 1) >> 1;
            for (int i = 0; i < iters; ++i) {
                int leN = le + 2;
                float2 xB = make_float2(0.f, 0.f);
                if (leN < ne) {
                    int sN = __shfl(srcv, leN, 64);
                    xB = xin[(size_t)sN * CINC + c];
                }
                if (le < ne) {
                    const float4* sp = myst + le*9;
                    #pragma unroll
                    for (int j = 0; j < 9; ++j) {
                        float4 s = sp[j];
                        acc[2*j].x   = fmaf(s.x, xA.x, fmaf(-s.y, xA.y, acc[2*j].x));
                        acc[2*j].y   = fmaf(s.x, xA.y, fmaf( s.y, xA.x, acc[2*j].y));
                        acc[2*j+1].x = fmaf(s.z, xA.x, fmaf(-s.w, xA.y, acc[2*j+1].x));
                        acc[2*j+1].y = fmaf(s.z, xA.y, fmaf( s.w, xA.x, acc[2*j+1].y));
                    }
                }
                xA = xB; le = leN;
            }
        }
        // merge the two halves (half1 -> half0)
        #pragma unroll
        for (int k = 0; k < RM; ++k) {
            acc[k].x += __shfl_down(acc[k].x, 32, 64);
            acc[k].y += __shfl_down(acc[k].y, 32, 64);
        }
        if (h == 0) {
            #pragma unroll
            for (int k = 0; k < RM; ++k)
                agg[g*KK + k*32 + c] = acc[k];
        }
    }
    __syncthreads();

    // ---- einsum: out[n,d] = sum_k agg[n,k] * Wc[k,d] ----
    int ch = t >> 4;                        // 16 chunks of 36 k's
    int dp = (t & 15) * 2;                  // d-pair base
    int kb = ch * 36;
    float2 p0[NPB], p1[NPB];
    #pragma unroll
    for (int j = 0; j < NPB; ++j) { p0[j] = make_float2(0.f,0.f); p1[j] = make_float2(0.f,0.f); }
    #pragma unroll 6
    for (int q = 0; q < 36; ++q) {
        float4 w = *(const float4*)(Wc + (size_t)(kb + q) * COUTC + dp);
        #pragma unroll
        for (int j = 0; j < NPB; ++j) {
            float2 a = agg[j*KK + kb + q];
            p0[j].x += a.x*w.x - a.y*w.y;
            p0[j].y += a.x*w.y + a.y*w.x;
            p1[j].x += a.x*w.z - a.y*w.w;
            p1[j].y += a.x*w.w + a.y*w.z;
        }
    }
    __syncthreads();                        // all agg reads done; reuse as part
    float2* part = smem;                    // [16][PART_STRIDE] : [ch][j*32+d]
    #pragma unroll
    for (int j = 0; j < NPB; ++j)
        *(float4*)&part[(size_t)ch*PART_STRIDE + j*32 + dp] =
            make_float4(p0[j].x, p0[j].y, p1[j].x, p1[j].y);
    __syncthreads();

    // ---- reduce chunks, residual, nonlinearity ----
    if (t < NPB*32) {
        int j = t >> 5, d = t & 31;
        int n = blockIdx.x*NPB + j;
        float2 hv = make_float2(0.f, 0.f);
        #pragma unroll
        for (int c2 = 0; c2 < 16; ++c2) {
            float2 vv = part[(size_t)c2*PART_STRIDE + j*32 + d];
            hv.x += vv.x; hv.y += vv.y;
        }
        if (FINAL) {
            const float2* xr = xres + (size_t)n * CINC;
            #pragma unroll
            for (int c = 0; c < CINC; ++c) {
                float2 xv = xr[c];
                float2 w = resw[c*COUTC + d];
                hv.x += xv.x*w.x - xv.y*w.y;
                hv.y += xv.x*w.y + xv.y*w.x;
            }
        }
        float mag = sqrtf(hv.x*hv.x + hv.y*hv.y);
        float num = mag + bias[d]; if (num < 0.f) num = 0.f;
        float den = (mag > EPSV) ? mag : EPSV;
        float f = num / den;
        out[(size_t)n*COUTC + d] = make_float2(f*hv.x, f*hv.y);
    }
}

// ---------------- launch ----------------

extern "C" void kernel_launch(void* const* d_in, const int* in_sizes, int n_in,
                              void* d_out, int out_size, void* d_ws, size_t ws_size,
                              hipStream_t stream) {
    const float2* xc   = (const float2*)d_in[0];   // (N,32,2) -> complex
    const int*   edges = (const int*)  d_in[1];    // (E,2)
    const float4* stenc4 = (const float4*)d_in[2]; // (E,6,3,2) -> (E,9) float4
    const float* w1    = (const float*)d_in[3];
    const float* off1  = (const float*)d_in[4];
    const float* b1    = (const float*)d_in[5];
    const float* w2    = (const float*)d_in[6];
    const float* off2  = (const float*)d_in[7];
    const float* b2    = (const float*)d_in[8];
    const float2* resw = (const float2*)d_in[9];   // (32,32) complex
    float2* out = (float2*)d_out;

    char* ws = (char*)d_ws;
    size_t o = 0;
    auto alloc = [&](size_t bytes) {
        o = (o + 255) & ~(size_t)255;
        size_t r = o; o += bytes; return r;
    };
    int*    counts = (int*)   (ws + alloc((NN+1)*sizeof(int)));
    int*    cursor = (int*)   (ws + alloc(NN*sizeof(int)));
    int*    srcs   = (int*)   (ws + alloc(EE*sizeof(int)));
    int*    eids   = (int*)   (ws + alloc(EE*sizeof(int)));
    float2* Wc1    = (float2*)(ws + alloc((size_t)KK*COUTC*sizeof(float2)));
    float2* Wc2    = (float2*)(ws + alloc((size_t)KK*COUTC*sizeof(float2)));
    float2* h      = (float2*)(ws + alloc((size_t)NN*COUTC*sizeof(float2)));
    (void)ws_size; (void)in_sizes; (void)n_in; (void)out_size;

    hipMemsetAsync(counts, 0, (NN+1)*sizeof(int), stream);
    k_prep   <<<(EE+255)/256, 256, 0, stream>>>(edges, counts, w1, off1, w2, off2, Wc1, Wc2);
    k_scan   <<<1, 1024, 0, stream>>>(counts, cursor);
    k_scatter<<<(EE+255)/256, 256, 0, stream>>>(edges, cursor, srcs, eids);

    k_conv<false><<<NN/NPB, 256, 0, stream>>>(xc, counts, srcs, eids, stenc4, Wc1, b1,
                                              nullptr, nullptr, h);
    k_conv<true> <<<NN/NPB, 256, 0, stream>>>(h, counts, srcs, eids, stenc4, Wc2, b2,
                                              xc, resw, out);
}